// Round 1
// baseline (1283.637 us; speedup 1.0000x reference)
//
#include <hip/hip_runtime.h>
#include <hip/hip_bf16.h>

#define N 384
#define HIDN 128
#define NHD 8
#define DHD 16
#define NRB 64
#define CUTF 10.0f

// ws layout (floats)
#define WS_Q 0
#define WS_K (WS_Q + N*HIDN)
#define WS_V (WS_K + N*HIDN)
#define WS_QP (WS_V + N*HIDN)
#define WS_KP (WS_QP + N*NHD*HIDN)
#define WS_GATE (WS_KP + N*NHD*HIDN)
#define WS_UPD (WS_GATE + N*NHD)
#define WS_CPART (WS_UPD + N*HIDN)
#define WS_SCORES (WS_CPART + NHD*N*3)

__device__ __forceinline__ float siluf(float x) { return x / (1.0f + __expf(-x)); }

__device__ __forceinline__ float wave_sum(float v) {
    for (int o = 32; o; o >>= 1) v += __shfl_down(v, o, 64);
    return v;
}

// K1: q,k,v = ef @ wq/wk/wv
__global__ __launch_bounds__(128) void k_qkv(const float* __restrict__ ef,
    const float* __restrict__ wq, const float* __restrict__ wk, const float* __restrict__ wv,
    float* __restrict__ q, float* __restrict__ k, float* __restrict__ v) {
    __shared__ float sE[HIDN];
    int i = blockIdx.x, t = threadIdx.x;
    sE[t] = ef[i * HIDN + t];
    __syncthreads();
    float aq = 0.f, ak = 0.f, av = 0.f;
#pragma unroll 8
    for (int c = 0; c < HIDN; c++) {
        float e = sE[c];
        aq += e * wq[c * HIDN + t];
        ak += e * wk[c * HIDN + t];
        av += e * wv[c * HIDN + t];
    }
    q[i * HIDN + t] = aq; k[i * HIDN + t] = ak; v[i * HIDN + t] = av;
}

// K2: Qp[i,h,c] = q[i,h,:]@W1_q ; Kp = k@W1_k ; gates[i,h]
__global__ __launch_bounds__(128) void k_prep(const float* __restrict__ q,
    const float* __restrict__ k, const float* __restrict__ v,
    const float* __restrict__ aw1,
    const float* __restrict__ gw1, const float* __restrict__ gb1,
    const float* __restrict__ gw2, const float* __restrict__ gb2,
    float* __restrict__ Qp, float* __restrict__ Kp, float* __restrict__ gates) {
    __shared__ float sQ[HIDN], sK[HIDN], sV[HIDN];
    __shared__ float sRed[2];
    int i = blockIdx.x, c = threadIdx.x;
    sQ[c] = q[i * HIDN + c]; sK[c] = k[i * HIDN + c]; sV[c] = v[i * HIDN + c];
    __syncthreads();
    for (int h = 0; h < NHD; h++) {
        float accq = 0.f, acck = 0.f;
#pragma unroll
        for (int d = 0; d < DHD; d++) {
            accq += sQ[h * DHD + d] * aw1[d * HIDN + c];
            acck += sK[h * DHD + d] * aw1[(DHD + d) * HIDN + c];
        }
        Qp[(i * NHD + h) * HIDN + c] = accq;
        Kp[(i * NHD + h) * HIDN + c] = acck;
        float t = gb1[c];
#pragma unroll
        for (int d = 0; d < DHD; d++) t += sV[h * DHD + d] * gw1[d * HIDN + c];
        float contrib = siluf(t) * gw2[c];
        float s = wave_sum(contrib);
        if ((c & 63) == 0) sRed[c >> 6] = s;
        __syncthreads();
        if (c == 0) gates[i * NHD + h] = 1.0f / (1.0f + __expf(-(sRed[0] + sRed[1] + gb2[0])));
        __syncthreads();
    }
}

// K3: fused per-pair MLP -> scores[h][i][j]
#define GROUPS 4
#define JPB 8
__global__ __launch_bounds__(512) void k_scores(
    const float* __restrict__ coords, const float* __restrict__ mask,
    const float* __restrict__ centers, const float* __restrict__ widths,
    const float* __restrict__ aw1, const float* __restrict__ ab1,
    const float* __restrict__ aw2, const float* __restrict__ ab2,
    const float* __restrict__ aw3, const float* __restrict__ ab3,
    const float* __restrict__ Qp, const float* __restrict__ Kp,
    float* __restrict__ scores) {
    __shared__ __hip_bfloat16 sW2[HIDN * HIDN];   // 32KB, [cp][c]
    __shared__ __hip_bfloat16 sWr[NRB * HIDN];    // 16KB, [r][c]
    __shared__ __align__(16) float sX1[GROUPS][HIDN][4];   // 8KB
    __shared__ __align__(16) float sRbf[GROUPS][NRB][4];   // 4KB
    __shared__ float sDD[GROUPS][4][2];
    __shared__ float sRed[GROUPS][2][4];
    int tid = threadIdx.x;
    int g = tid >> 7, c = tid & 127;
    int i = blockIdx.y;
    int jg0 = blockIdx.x * (GROUPS * JPB) + g * JPB;

    for (int idx = tid; idx < HIDN * HIDN; idx += 512) sW2[idx] = __float2bfloat16(aw2[idx]);
    for (int idx = tid; idx < NRB * HIDN; idx += 512) sWr[idx] = __float2bfloat16(aw1[32 * HIDN + idx]);

    float qp[NHD], w3[NHD];
#pragma unroll
    for (int h = 0; h < NHD; h++) {
        qp[h] = Qp[(i * NHD + h) * HIDN + c];
        w3[h] = aw3[c * NHD + h];
    }
    float b1c = ab1[c], b2c = ab2[c], w1d = aw1[96 * HIDN + c];
    float cix = coords[i * 3], ciy = coords[i * 3 + 1], ciz = coords[i * 3 + 2];
    __syncthreads();

    for (int chunk = 0; chunk < JPB / 4; chunk++) {
        int j0 = jg0 + chunk * 4;
        if (c < 4) {
            int j = j0 + c;
            float jx = coords[j * 3], jy = coords[j * 3 + 1], jz = coords[j * 3 + 2];
            float dx = cix - jx, dy = ciy - jy, dz = ciz - jz;
            float dist = sqrtf(dx * dx + dy * dy + dz * dz) + 1e-8f;
            dist = fminf(fmaxf(dist, 1e-8f), 1e8f);
            float dot = cix * jx + ciy * jy + ciz * jz;
            dot = fminf(fmaxf(dot, -1e8f), 1e8f);
            sDD[g][c][0] = dist; sDD[g][c][1] = dot;
        }
        __syncthreads();
        {
            int r = c & 63;
            int pbase = c >> 6;
            float cr = centers[r], rw = widths[r];
#pragma unroll
            for (int pp = 0; pp < 2; pp++) {
                int p = pbase + pp * 2;
                float d = sDD[g][p][0];
                float t = d - cr;
                sRbf[g][r][p] = (d <= CUTF) ? __expf(-rw * t * t) : 0.0f;
            }
        }
        __syncthreads();
        float R0 = b1c + sDD[g][0][1] * w1d;
        float R1 = b1c + sDD[g][1][1] * w1d;
        float R2 = b1c + sDD[g][2][1] * w1d;
        float R3 = b1c + sDD[g][3][1] * w1d;
#pragma unroll 8
        for (int r = 0; r < NRB; r++) {
            float4 rb = *(const float4*)&sRbf[g][r][0];
            float w = __bfloat162float(sWr[r * HIDN + c]);
            R0 += rb.x * w; R1 += rb.y * w; R2 += rb.z * w; R3 += rb.w * w;
        }
        for (int h = 0; h < NHD; h++) {
            float4 x1;
            x1.x = siluf(qp[h] + Kp[((j0 + 0) * NHD + h) * HIDN + c] + R0);
            x1.y = siluf(qp[h] + Kp[((j0 + 1) * NHD + h) * HIDN + c] + R1);
            x1.z = siluf(qp[h] + Kp[((j0 + 2) * NHD + h) * HIDN + c] + R2);
            x1.w = siluf(qp[h] + Kp[((j0 + 3) * NHD + h) * HIDN + c] + R3);
            *(float4*)&sX1[g][c][0] = x1;
            __syncthreads();
            float a0 = b2c, a1 = b2c, a2 = b2c, a3 = b2c;
#pragma unroll 8
            for (int cp = 0; cp < HIDN; cp++) {
                float4 x = *(const float4*)&sX1[g][cp][0];
                float w = __bfloat162float(sW2[cp * HIDN + c]);
                a0 += x.x * w; a1 += x.y * w; a2 += x.z * w; a3 += x.w * w;
            }
            float p0 = siluf(a0) * w3[h], p1 = siluf(a1) * w3[h];
            float p2 = siluf(a2) * w3[h], p3 = siluf(a3) * w3[h];
            p0 = wave_sum(p0); p1 = wave_sum(p1); p2 = wave_sum(p2); p3 = wave_sum(p3);
            if ((c & 63) == 0) {
                int wv = c >> 6;
                sRed[g][wv][0] = p0; sRed[g][wv][1] = p1;
                sRed[g][wv][2] = p2; sRed[g][wv][3] = p3;
            }
            __syncthreads();
            if (c < 4) {
                float s = sRed[g][0][c] + sRed[g][1][c] + ab3[h] + mask[i * N + j0 + c];
                s = fminf(fmaxf(s, -1e9f), 1e9f);
                scores[(h * N + i) * N + j0 + c] = s;
            }
        }
    }
}

// K4: softmax + attn@V + coord partials. blockIdx.x = h*N+i
__global__ __launch_bounds__(128) void k_attn(
    const float* __restrict__ scores, const float* __restrict__ v,
    const float* __restrict__ gates, const float* __restrict__ coords,
    float* __restrict__ upd, float* __restrict__ cpart) {
    __shared__ float sA[N];
    __shared__ float sF[DHD][8];
    __shared__ float sR[2];
    __shared__ float sC[2][3];
    int bi = blockIdx.x;
    int h = bi / N, i = bi % N;
    int t = threadIdx.x;
    const float* srow = scores + bi * N;
    float s0 = srow[t], s1 = srow[t + 128], s2 = srow[t + 256];
    float m = fmaxf(s0, fmaxf(s1, s2));
    for (int o = 32; o; o >>= 1) m = fmaxf(m, __shfl_down(m, o, 64));
    if ((t & 63) == 0) sR[t >> 6] = m;
    __syncthreads();
    m = fmaxf(sR[0], sR[1]);
    __syncthreads();
    float e0 = __expf(s0 - m), e1 = __expf(s1 - m), e2 = __expf(s2 - m);
    float ss = wave_sum(e0 + e1 + e2);
    if ((t & 63) == 0) sR[t >> 6] = ss;
    __syncthreads();
    float inv = 1.0f / (sR[0] + sR[1]);
    sA[t] = e0 * inv; sA[t + 128] = e1 * inv; sA[t + 256] = e2 * inv;
    __syncthreads();
    int d = t & 15, grp = t >> 4;
    float f = 0.f;
    for (int j = grp; j < N; j += 8) f += sA[j] * v[j * HIDN + h * DHD + d];
    sF[d][grp] = f;
    float cix = coords[i * 3], ciy = coords[i * 3 + 1], ciz = coords[i * 3 + 2];
    float cx = 0.f, cy = 0.f, cz = 0.f;
    for (int j = t; j < N; j += 128) {
        float a = sA[j];
        cx += a * (cix - coords[j * 3]);
        cy += a * (ciy - coords[j * 3 + 1]);
        cz += a * (ciz - coords[j * 3 + 2]);
    }
    cx = wave_sum(cx); cy = wave_sum(cy); cz = wave_sum(cz);
    if ((t & 63) == 0) { sC[t >> 6][0] = cx; sC[t >> 6][1] = cy; sC[t >> 6][2] = cz; }
    __syncthreads();
    if (t < DHD) {
        float acc = 0.f;
#pragma unroll
        for (int gq = 0; gq < 8; gq++) acc += sF[t][gq];
        upd[i * HIDN + h * DHD + t] = acc;
    }
    if (t == 0) {
        float gi = gates[i * NHD + h] * (1.0f / NHD);
        cpart[(h * N + i) * 3 + 0] = gi * (sC[0][0] + sC[1][0]);
        cpart[(h * N + i) * 3 + 1] = gi * (sC[0][1] + sC[1][1]);
        cpart[(h * N + i) * 3 + 2] = gi * (sC[0][2] + sC[1][2]);
    }
}

// K5: y = ef + upd@wo + bo, LayerNorm; coords out
__global__ __launch_bounds__(128) void k_out(
    const float* __restrict__ ef, const float* __restrict__ upd,
    const float* __restrict__ wo, const float* __restrict__ bo,
    const float* __restrict__ lng, const float* __restrict__ lnb,
    const float* __restrict__ coords, const float* __restrict__ cpart,
    float* __restrict__ out) {
    __shared__ float sU[HIDN];
    __shared__ float sR[2];
    int i = blockIdx.x, c = threadIdx.x;
    sU[c] = upd[i * HIDN + c];
    __syncthreads();
    float y = ef[i * HIDN + c] + bo[c];
#pragma unroll 8
    for (int cp = 0; cp < HIDN; cp++) y += sU[cp] * wo[cp * HIDN + c];
    float s = wave_sum(y);
    if ((c & 63) == 0) sR[c >> 6] = s;
    __syncthreads();
    float mu = (sR[0] + sR[1]) * (1.0f / HIDN);
    __syncthreads();
    float dv = y - mu;
    float s2 = wave_sum(dv * dv);
    if ((c & 63) == 0) sR[c >> 6] = s2;
    __syncthreads();
    float var = (sR[0] + sR[1]) * (1.0f / HIDN);
    out[i * HIDN + c] = dv * rsqrtf(var + 1e-5f) * lng[c] + lnb[c];
    if (c < 3) {
        float acc = coords[i * 3 + c];
#pragma unroll
        for (int h = 0; h < NHD; h++) acc += cpart[(h * N + i) * 3 + c];
        out[N * HIDN + i * 3 + c] = acc;
    }
}

extern "C" void kernel_launch(void* const* d_in, const int* in_sizes, int n_in,
                              void* d_out, int out_size, void* d_ws, size_t ws_size,
                              hipStream_t stream) {
    const float* ef      = (const float*)d_in[0];
    const float* coords  = (const float*)d_in[1];
    const float* mask    = (const float*)d_in[2];
    const float* wq      = (const float*)d_in[3];
    const float* wk      = (const float*)d_in[4];
    const float* wv      = (const float*)d_in[5];
    const float* centers = (const float*)d_in[6];
    const float* widths  = (const float*)d_in[7];
    const float* aw1     = (const float*)d_in[8];
    const float* ab1     = (const float*)d_in[9];
    const float* aw2     = (const float*)d_in[10];
    const float* ab2     = (const float*)d_in[11];
    const float* aw3     = (const float*)d_in[12];
    const float* ab3     = (const float*)d_in[13];
    const float* gw1     = (const float*)d_in[14];
    const float* gb1     = (const float*)d_in[15];
    const float* gw2     = (const float*)d_in[16];
    const float* gb2     = (const float*)d_in[17];
    const float* wo      = (const float*)d_in[18];
    const float* bo      = (const float*)d_in[19];
    const float* lng     = (const float*)d_in[20];
    const float* lnb     = (const float*)d_in[21];
    float* ws = (float*)d_ws;
    float* q      = ws + WS_Q;
    float* k      = ws + WS_K;
    float* v      = ws + WS_V;
    float* Qp     = ws + WS_QP;
    float* Kp     = ws + WS_KP;
    float* gates  = ws + WS_GATE;
    float* upd    = ws + WS_UPD;
    float* cpart  = ws + WS_CPART;
    float* scores = ws + WS_SCORES;
    float* out = (float*)d_out;

    k_qkv<<<N, 128, 0, stream>>>(ef, wq, wk, wv, q, k, v);
    k_prep<<<N, 128, 0, stream>>>(q, k, v, aw1, gw1, gb1, gw2, gb2, Qp, Kp, gates);
    k_scores<<<dim3(N / (GROUPS * JPB), N), 512, 0, stream>>>(
        coords, mask, centers, widths, aw1, ab1, aw2, ab2, aw3, ab3, Qp, Kp, scores);
    k_attn<<<NHD * N, 128, 0, stream>>>(scores, v, gates, coords, upd, cpart);
    k_out<<<N, 128, 0, stream>>>(ef, upd, wo, bo, lng, lnb, coords, cpart, out);
}

// Round 2
// 308.454 us; speedup vs baseline: 4.1615x; 4.1615x over previous
//
#include <hip/hip_runtime.h>
#include <hip/hip_bf16.h>

#define N 384
#define HIDN 128
#define NHD 8
#define DHD 16
#define NRB 64
#define CUTF 10.0f

// ws layout (floats)
#define WS_Q 0
#define WS_K (WS_Q + N*HIDN)
#define WS_V (WS_K + N*HIDN)
#define WS_QP (WS_V + N*HIDN)
#define WS_KP (WS_QP + N*NHD*HIDN)
#define WS_GATE (WS_KP + N*NHD*HIDN)
#define WS_UPD (WS_GATE + N*NHD)
#define WS_CPART (WS_UPD + N*HIDN)
#define WS_SCORES (WS_CPART + NHD*N*3)

typedef short bf16x8 __attribute__((ext_vector_type(8)));
typedef float floatx4 __attribute__((ext_vector_type(4)));
#define MFMA16(a, b, c) __builtin_amdgcn_mfma_f32_16x16x32_bf16(a, b, c, 0, 0, 0)

__device__ __forceinline__ float siluf(float x) { return x / (1.0f + __expf(-x)); }
__device__ __forceinline__ float silu_fast(float x) {
    return x * __builtin_amdgcn_rcpf(1.0f + __expf(-x));
}
__device__ __forceinline__ short f2bf(float f) {
    unsigned int b = __float_as_uint(f);
    unsigned int r = (b + 0x7fffu + ((b >> 16) & 1u)) >> 16;
    return (short)r;
}

__device__ __forceinline__ float wave_sum(float v) {
    for (int o = 32; o; o >>= 1) v += __shfl_down(v, o, 64);
    return v;
}

// K1: q,k,v = ef @ wq/wk/wv
__global__ __launch_bounds__(128) void k_qkv(const float* __restrict__ ef,
    const float* __restrict__ wq, const float* __restrict__ wk, const float* __restrict__ wv,
    float* __restrict__ q, float* __restrict__ k, float* __restrict__ v) {
    __shared__ float sE[HIDN];
    int i = blockIdx.x, t = threadIdx.x;
    sE[t] = ef[i * HIDN + t];
    __syncthreads();
    float aq = 0.f, ak = 0.f, av = 0.f;
#pragma unroll 8
    for (int c = 0; c < HIDN; c++) {
        float e = sE[c];
        aq += e * wq[c * HIDN + t];
        ak += e * wk[c * HIDN + t];
        av += e * wv[c * HIDN + t];
    }
    q[i * HIDN + t] = aq; k[i * HIDN + t] = ak; v[i * HIDN + t] = av;
}

// K2: Qp[i,h,c] = q[i,h,:]@W1_q ; Kp = k@W1_k ; gates[i,h]
__global__ __launch_bounds__(128) void k_prep(const float* __restrict__ q,
    const float* __restrict__ k, const float* __restrict__ v,
    const float* __restrict__ aw1,
    const float* __restrict__ gw1, const float* __restrict__ gb1,
    const float* __restrict__ gw2, const float* __restrict__ gb2,
    float* __restrict__ Qp, float* __restrict__ Kp, float* __restrict__ gates) {
    __shared__ float sQ[HIDN], sK[HIDN], sV[HIDN];
    __shared__ float sRed[2];
    int i = blockIdx.x, c = threadIdx.x;
    sQ[c] = q[i * HIDN + c]; sK[c] = k[i * HIDN + c]; sV[c] = v[i * HIDN + c];
    __syncthreads();
    for (int h = 0; h < NHD; h++) {
        float accq = 0.f, acck = 0.f;
#pragma unroll
        for (int d = 0; d < DHD; d++) {
            accq += sQ[h * DHD + d] * aw1[d * HIDN + c];
            acck += sK[h * DHD + d] * aw1[(DHD + d) * HIDN + c];
        }
        Qp[(i * NHD + h) * HIDN + c] = accq;
        Kp[(i * NHD + h) * HIDN + c] = acck;
        float t = gb1[c];
#pragma unroll
        for (int d = 0; d < DHD; d++) t += sV[h * DHD + d] * gw1[d * HIDN + c];
        float contrib = siluf(t) * gw2[c];
        float s = wave_sum(contrib);
        if ((c & 63) == 0) sRed[c >> 6] = s;
        __syncthreads();
        if (c == 0) gates[i * NHD + h] = 1.0f / (1.0f + __expf(-(sRed[0] + sRed[1] + gb2[0])));
        __syncthreads();
    }
}

// ---------------- K3: MFMA scores kernel ----------------
// LDS byte offsets
#define OFF_W1RT 0            // 128 rows(n) x 72 bf16 (stride 144B) = 18432
#define OFF_QP   18432        // 8x128 f32 = 4096
#define OFF_W3T  22528        // 8x128 f32 = 4096  (w3T[h][c])
#define OFF_B1   26624        // 128 f32 = 512
#define OFF_W1D  27136        // 128 f32 = 512
#define OFF_B2   27648        // 128 f32 = 512
#define OFF_AB3  28160        // 8 f32 = 32
#define OFF_SDD  28192        // 16 x {dist,dot} = 128
#define OFF_RBF  28320        // 16 rows x 72 bf16 (stride 144B) = 2304
#define OFF_R    30624        // 16 rows x 132 f32 (stride 528B) = 8448
#define OFF_X1   39072        // 64 rows x 136 bf16 (stride 272B) = 17408
#define SMEM_SZ  56480
#define OFF_STAGE 0           // W2T staging: 128 rows x 136 bf16 = 34816 (overlaid, used before others)

__global__ __launch_bounds__(256, 2) void k_scores_mfma(
    const float* __restrict__ coords, const float* __restrict__ mask,
    const float* __restrict__ centers, const float* __restrict__ widths,
    const float* __restrict__ aw1, const float* __restrict__ ab1,
    const float* __restrict__ aw2, const float* __restrict__ ab2,
    const float* __restrict__ aw3, const float* __restrict__ ab3,
    const float* __restrict__ Qp, const float* __restrict__ Kp,
    float* __restrict__ scores) {
    __shared__ __align__(16) char smem[SMEM_SZ];
    const int t = threadIdx.x;
    const int lane = t & 63;
    const int w = t >> 6;          // wave id 0..3
    const int l15 = lane & 15;
    const int quad = lane >> 4;
    const int i = blockIdx.y;
    const int jb = blockIdx.x * 128;

    // phase0: stage W2T (bf16, [n][k], row stride 136 bf16) then pull B-frags to VGPRs
    for (int idx = t; idx < HIDN * HIDN; idx += 256) {
        int k = idx >> 7, n = idx & 127;
        *(short*)(smem + OFF_STAGE + n * 272 + k * 2) = f2bf(aw2[idx]);
    }
    __syncthreads();
    bf16x8 BW2[8][4];
#pragma unroll
    for (int ct = 0; ct < 8; ct++)
#pragma unroll
        for (int ks = 0; ks < 4; ks++)
            BW2[ct][ks] = *(const bf16x8*)(smem + OFF_STAGE + (ct * 16 + l15) * 272 + ks * 64 + quad * 16);
    __syncthreads();
    // phase1: resident tables (overwrite staging region)
    for (int idx = t; idx < NRB * HIDN; idx += 256) {
        int r = idx >> 7, n = idx & 127;
        *(short*)(smem + OFF_W1RT + n * 144 + r * 2) = f2bf(aw1[32 * HIDN + idx]);
    }
    for (int idx = t; idx < NHD * HIDN; idx += 256)
        *(float*)(smem + OFF_QP + idx * 4) = Qp[(size_t)i * NHD * HIDN + idx];
    for (int idx = t; idx < HIDN * NHD; idx += 256) {
        int c = idx >> 3, h = idx & 7;
        *(float*)(smem + OFF_W3T + (h * 128 + c) * 4) = aw3[idx];
    }
    if (t < 128) {
        *(float*)(smem + OFF_B1 + t * 4) = ab1[t];
        *(float*)(smem + OFF_W1D + t * 4) = aw1[96 * HIDN + t];
        *(float*)(smem + OFF_B2 + t * 4) = ab2[t];
    }
    if (t < 8) *(float*)(smem + OFF_AB3 + t * 4) = ab3[t];
    const float cix = coords[i * 3], ciy = coords[i * 3 + 1], ciz = coords[i * 3 + 2];
    __syncthreads();

    for (int ch = 0; ch < 8; ch++) {
        const int j0 = jb + ch * 16;
        // (a) dist/dot for 16 j
        if (t < 16) {
            int j = j0 + t;
            float jx = coords[j * 3], jy = coords[j * 3 + 1], jz = coords[j * 3 + 2];
            float dx = cix - jx, dy = ciy - jy, dz = ciz - jz;
            float dist = sqrtf(dx * dx + dy * dy + dz * dz) + 1e-8f;
            dist = fminf(fmaxf(dist, 1e-8f), 1e8f);
            float dot = fminf(fmaxf(cix * jx + ciy * jy + ciz * jz, -1e8f), 1e8f);
            *(float*)(smem + OFF_SDD + t * 8) = dist;
            *(float*)(smem + OFF_SDD + t * 8 + 4) = dot;
        }
        __syncthreads();
        // (b) rbf (bf16, A-operand layout rows j, stride 144B)
        {
            int r = t & 63;
            float cr = centers[r], rw = widths[r];
#pragma unroll
            for (int p = 0; p < 4; p++) {
                int j = (t >> 6) + p * 4;
                float d = *(const float*)(smem + OFF_SDD + j * 8);
                float dd = d - cr;
                float val = (d <= CUTF) ? __expf(-rw * dd * dd) : 0.0f;
                *(short*)(smem + OFF_RBF + j * 144 + r * 2) = f2bf(val);
            }
        }
        __syncthreads();
        // (c) R = b1 + rbf@W1r + dot*w1d  via MFMA (K=64); wave w -> col-tiles {w, w+4}
        {
            bf16x8 ra0 = *(const bf16x8*)(smem + OFF_RBF + l15 * 144 + quad * 16);
            bf16x8 ra1 = *(const bf16x8*)(smem + OFF_RBF + l15 * 144 + 64 + quad * 16);
#pragma unroll
            for (int cc = 0; cc < 2; cc++) {
                int ct = w + cc * 4;
                floatx4 acc = {0.f, 0.f, 0.f, 0.f};
                bf16x8 b0 = *(const bf16x8*)(smem + OFF_W1RT + (ct * 16 + l15) * 144 + quad * 16);
                bf16x8 b1f = *(const bf16x8*)(smem + OFF_W1RT + (ct * 16 + l15) * 144 + 64 + quad * 16);
                acc = MFMA16(ra0, b0, acc);
                acc = MFMA16(ra1, b1f, acc);
                int c = ct * 16 + l15;
                float b1v = *(const float*)(smem + OFF_B1 + c * 4);
                float w1dv = *(const float*)(smem + OFF_W1D + c * 4);
#pragma unroll
                for (int r = 0; r < 4; r++) {
                    int j = quad * 4 + r;
                    float dotv = *(const float*)(smem + OFF_SDD + j * 8 + 4);
                    *(float*)(smem + OFF_R + j * 528 + c * 4) = acc[r] + b1v + dotv * w1dv;
                }
            }
        }
        __syncthreads();
        // (d) two halves of 4 heads each
#pragma unroll
        for (int hh = 0; hh < 2; hh++) {
            // build x1 rows (bf16, stride 272B): x1[hl*16+j][c] = silu(Qp+Kp+R)
#pragma unroll
            for (int kk = 0; kk < 8; kk++) {
                int idx = t + kk * 256;
                int c4 = idx & 31, j = (idx >> 5) & 15, hl = idx >> 9;
                int h = hh * 4 + hl;
                float4 kp = *(const float4*)(Kp + ((size_t)(j0 + j) * NHD + h) * HIDN + c4 * 4);
                float4 qp = *(const float4*)(smem + OFF_QP + (h * 128 + c4 * 4) * 4);
                float4 rr = *(const float4*)(smem + OFF_R + j * 528 + c4 * 16);
                float x0 = silu_fast(kp.x + qp.x + rr.x);
                float x1 = silu_fast(kp.y + qp.y + rr.y);
                float x2 = silu_fast(kp.z + qp.z + rr.z);
                float x3 = silu_fast(kp.w + qp.w + rr.w);
                int2 pk;
                pk.x = (int)(unsigned short)f2bf(x0) | ((int)(unsigned short)f2bf(x1) << 16);
                pk.y = (int)(unsigned short)f2bf(x2) | ((int)(unsigned short)f2bf(x3) << 16);
                *(int2*)(smem + OFF_X1 + (hl * 16 + j) * 272 + c4 * 8) = pk;
            }
            __syncthreads();
            // strip MFMA: wave w -> head h = hh*4 + w, 16 rows x 128 cols, K=128
            {
                const int h = hh * 4 + w;
                const char* xb = smem + OFF_X1 + (w * 16 + l15) * 272;
                bf16x8 a0 = *(const bf16x8*)(xb + quad * 16);
                bf16x8 a1 = *(const bf16x8*)(xb + 64 + quad * 16);
                bf16x8 a2 = *(const bf16x8*)(xb + 128 + quad * 16);
                bf16x8 a3 = *(const bf16x8*)(xb + 192 + quad * 16);
                float part[4] = {0.f, 0.f, 0.f, 0.f};
#pragma unroll
                for (int ct = 0; ct < 8; ct++) {
                    floatx4 acc = {0.f, 0.f, 0.f, 0.f};
                    acc = MFMA16(a0, BW2[ct][0], acc);
                    acc = MFMA16(a1, BW2[ct][1], acc);
                    acc = MFMA16(a2, BW2[ct][2], acc);
                    acc = MFMA16(a3, BW2[ct][3], acc);
                    int c = ct * 16 + l15;
                    float b2v = *(const float*)(smem + OFF_B2 + c * 4);
                    float w3v = *(const float*)(smem + OFF_W3T + (h * 128 + c) * 4);
#pragma unroll
                    for (int r = 0; r < 4; r++) {
                        float a = acc[r] + b2v;
                        part[r] += silu_fast(a) * w3v;
                    }
                }
#pragma unroll
                for (int off = 1; off < 16; off <<= 1) {
#pragma unroll
                    for (int r = 0; r < 4; r++) part[r] += __shfl_xor(part[r], off, 64);
                }
                if (l15 == 0) {
                    float ab3v = *(const float*)(smem + OFF_AB3 + h * 4);
#pragma unroll
                    for (int r = 0; r < 4; r++) {
                        int j = quad * 4 + r;
                        float s = part[r] + ab3v + mask[(size_t)i * N + j0 + j];
                        s = fminf(fmaxf(s, -1e9f), 1e9f);
                        scores[((size_t)h * N + i) * N + j0 + j] = s;
                    }
                }
            }
            __syncthreads();
        }
    }
}

// K4: softmax + attn@V + coord partials. blockIdx.x = h*N+i
__global__ __launch_bounds__(128) void k_attn(
    const float* __restrict__ scores, const float* __restrict__ v,
    const float* __restrict__ gates, const float* __restrict__ coords,
    float* __restrict__ upd, float* __restrict__ cpart) {
    __shared__ float sA[N];
    __shared__ float sF[DHD][8];
    __shared__ float sR[2];
    __shared__ float sC[2][3];
    int bi = blockIdx.x;
    int h = bi / N, i = bi % N;
    int t = threadIdx.x;
    const float* srow = scores + (size_t)bi * N;
    float s0 = srow[t], s1 = srow[t + 128], s2 = srow[t + 256];
    float m = fmaxf(s0, fmaxf(s1, s2));
    for (int o = 32; o; o >>= 1) m = fmaxf(m, __shfl_down(m, o, 64));
    if ((t & 63) == 0) sR[t >> 6] = m;
    __syncthreads();
    m = fmaxf(sR[0], sR[1]);
    __syncthreads();
    float e0 = __expf(s0 - m), e1 = __expf(s1 - m), e2 = __expf(s2 - m);
    float ss = wave_sum(e0 + e1 + e2);
    if ((t & 63) == 0) sR[t >> 6] = ss;
    __syncthreads();
    float inv = 1.0f / (sR[0] + sR[1]);
    sA[t] = e0 * inv; sA[t + 128] = e1 * inv; sA[t + 256] = e2 * inv;
    __syncthreads();
    int d = t & 15, grp = t >> 4;
    float f = 0.f;
    for (int j = grp; j < N; j += 8) f += sA[j] * v[j * HIDN + h * DHD + d];
    sF[d][grp] = f;
    float cix = coords[i * 3], ciy = coords[i * 3 + 1], ciz = coords[i * 3 + 2];
    float cx = 0.f, cy = 0.f, cz = 0.f;
    for (int j = t; j < N; j += 128) {
        float a = sA[j];
        cx += a * (cix - coords[j * 3]);
        cy += a * (ciy - coords[j * 3 + 1]);
        cz += a * (ciz - coords[j * 3 + 2]);
    }
    cx = wave_sum(cx); cy = wave_sum(cy); cz = wave_sum(cz);
    if ((t & 63) == 0) { sC[t >> 6][0] = cx; sC[t >> 6][1] = cy; sC[t >> 6][2] = cz; }
    __syncthreads();
    if (t < DHD) {
        float acc = 0.f;
#pragma unroll
        for (int gq = 0; gq < 8; gq++) acc += sF[t][gq];
        upd[i * HIDN + h * DHD + t] = acc;
    }
    if (t == 0) {
        float gi = gates[i * NHD + h] * (1.0f / NHD);
        cpart[(h * N + i) * 3 + 0] = gi * (sC[0][0] + sC[1][0]);
        cpart[(h * N + i) * 3 + 1] = gi * (sC[0][1] + sC[1][1]);
        cpart[(h * N + i) * 3 + 2] = gi * (sC[0][2] + sC[1][2]);
    }
}

// K5: y = ef + upd@wo + bo, LayerNorm; coords out
__global__ __launch_bounds__(128) void k_out(
    const float* __restrict__ ef, const float* __restrict__ upd,
    const float* __restrict__ wo, const float* __restrict__ bo,
    const float* __restrict__ lng, const float* __restrict__ lnb,
    const float* __restrict__ coords, const float* __restrict__ cpart,
    float* __restrict__ out) {
    __shared__ float sU[HIDN];
    __shared__ float sR[2];
    int i = blockIdx.x, c = threadIdx.x;
    sU[c] = upd[i * HIDN + c];
    __syncthreads();
    float y = ef[i * HIDN + c] + bo[c];
#pragma unroll 8
    for (int cp = 0; cp < HIDN; cp++) y += sU[cp] * wo[cp * HIDN + c];
    float s = wave_sum(y);
    if ((c & 63) == 0) sR[c >> 6] = s;
    __syncthreads();
    float mu = (sR[0] + sR[1]) * (1.0f / HIDN);
    __syncthreads();
    float dv = y - mu;
    float s2 = wave_sum(dv * dv);
    if ((c & 63) == 0) sR[c >> 6] = s2;
    __syncthreads();
    float var = (sR[0] + sR[1]) * (1.0f / HIDN);
    out[i * HIDN + c] = dv * rsqrtf(var + 1e-5f) * lng[c] + lnb[c];
    if (c < 3) {
        float acc = coords[i * 3 + c];
#pragma unroll
        for (int h = 0; h < NHD; h++) acc += cpart[(h * N + i) * 3 + c];
        out[N * HIDN + i * 3 + c] = acc;
    }
}

extern "C" void kernel_launch(void* const* d_in, const int* in_sizes, int n_in,
                              void* d_out, int out_size, void* d_ws, size_t ws_size,
                              hipStream_t stream) {
    const float* ef      = (const float*)d_in[0];
    const float* coords  = (const float*)d_in[1];
    const float* mask    = (const float*)d_in[2];
    const float* wq      = (const float*)d_in[3];
    const float* wk      = (const float*)d_in[4];
    const float* wv      = (const float*)d_in[5];
    const float* centers = (const float*)d_in[6];
    const float* widths  = (const float*)d_in[7];
    const float* aw1     = (const float*)d_in[8];
    const float* ab1     = (const float*)d_in[9];
    const float* aw2     = (const float*)d_in[10];
    const float* ab2     = (const float*)d_in[11];
    const float* aw3     = (const float*)d_in[12];
    const float* ab3     = (const float*)d_in[13];
    const float* gw1     = (const float*)d_in[14];
    const float* gb1     = (const float*)d_in[15];
    const float* gw2     = (const float*)d_in[16];
    const float* gb2     = (const float*)d_in[17];
    const float* wo      = (const float*)d_in[18];
    const float* bo      = (const float*)d_in[19];
    const float* lng     = (const float*)d_in[20];
    const float* lnb     = (const float*)d_in[21];
    float* ws = (float*)d_ws;
    float* q      = ws + WS_Q;
    float* k      = ws + WS_K;
    float* v      = ws + WS_V;
    float* Qp     = ws + WS_QP;
    float* Kp     = ws + WS_KP;
    float* gates  = ws + WS_GATE;
    float* upd    = ws + WS_UPD;
    float* cpart  = ws + WS_CPART;
    float* scores = ws + WS_SCORES;
    float* out = (float*)d_out;

    k_qkv<<<N, 128, 0, stream>>>(ef, wq, wk, wv, q, k, v);
    k_prep<<<N, 128, 0, stream>>>(q, k, v, aw1, gw1, gb1, gw2, gb2, Qp, Kp, gates);
    k_scores_mfma<<<dim3(3, N), 256, 0, stream>>>(
        coords, mask, centers, widths, aw1, ab1, aw2, ab2, aw3, ab3, Qp, Kp, scores);
    k_attn<<<NHD * N, 128, 0, stream>>>(scores, v, gates, coords, upd, cpart);
    k_out<<<N, 128, 0, stream>>>(ef, upd, wo, bo, lng, lnb, coords, cpart, out);
}

// Round 3
// 298.563 us; speedup vs baseline: 4.2994x; 1.0331x over previous
//
#include <hip/hip_runtime.h>
#include <hip/hip_bf16.h>

#define N 384
#define HIDN 128
#define NHD 8
#define DHD 16
#define NRB 64
#define CUTF 10.0f

// ws layout (float slots)
#define WS_V 0
#define WS_QPB (WS_V + N*HIDN)                 // bf16 buffer: N*8*128 shorts
#define WS_KPB (WS_QPB + N*NHD*HIDN/2)        // bf16 buffer: N*8*128 shorts
#define WS_GATE (WS_KPB + N*NHD*HIDN/2)
#define WS_UPD (WS_GATE + N*NHD)
#define WS_SCORES (WS_UPD + N*HIDN)

typedef short bf16x8 __attribute__((ext_vector_type(8)));
typedef float floatx4 __attribute__((ext_vector_type(4)));
#define MFMA16(a, b, c) __builtin_amdgcn_mfma_f32_16x16x32_bf16(a, b, c, 0, 0, 0)

__device__ __forceinline__ float siluf(float x) { return x / (1.0f + __expf(-x)); }
__device__ __forceinline__ float silu_fast(float x) {
    return x * __builtin_amdgcn_rcpf(1.0f + __expf(-x));
}
__device__ __forceinline__ short f2bf(float f) {
    unsigned int b = __float_as_uint(f);
    unsigned int r = (b + 0x7fffu + ((b >> 16) & 1u)) >> 16;
    return (short)r;
}
__device__ __forceinline__ float bf2f(short s) {
    return __uint_as_float(((unsigned int)(unsigned short)s) << 16);
}
__device__ __forceinline__ float wave_sum(float v) {
    for (int o = 32; o; o >>= 1) v += __shfl_down(v, o, 64);
    return v;
}

// K1: fused qkv + Qp/Kp(bf16) + gates
__global__ __launch_bounds__(128) void k_pre(const float* __restrict__ ef,
    const float* __restrict__ wq, const float* __restrict__ wk, const float* __restrict__ wv,
    const float* __restrict__ aw1,
    const float* __restrict__ gw1, const float* __restrict__ gb1,
    const float* __restrict__ gw2, const float* __restrict__ gb2,
    float* __restrict__ v, unsigned short* __restrict__ Qpb,
    unsigned short* __restrict__ Kpb, float* __restrict__ gates) {
    __shared__ float sE[HIDN], sQ[HIDN], sK[HIDN], sV[HIDN];
    __shared__ float sRed[2];
    int i = blockIdx.x, t = threadIdx.x;
    sE[t] = ef[i * HIDN + t];
    __syncthreads();
    float aq = 0.f, ak = 0.f, av = 0.f;
#pragma unroll 8
    for (int c = 0; c < HIDN; c++) {
        float e = sE[c];
        aq += e * wq[c * HIDN + t];
        ak += e * wk[c * HIDN + t];
        av += e * wv[c * HIDN + t];
    }
    v[i * HIDN + t] = av;
    sQ[t] = aq; sK[t] = ak; sV[t] = av;
    __syncthreads();
    for (int h = 0; h < NHD; h++) {
        float accq = 0.f, acck = 0.f;
#pragma unroll
        for (int d = 0; d < DHD; d++) {
            accq += sQ[h * DHD + d] * aw1[d * HIDN + t];
            acck += sK[h * DHD + d] * aw1[(DHD + d) * HIDN + t];
        }
        Qpb[(i * NHD + h) * HIDN + t] = (unsigned short)f2bf(accq);
        Kpb[(i * NHD + h) * HIDN + t] = (unsigned short)f2bf(acck);
        float tt = gb1[t];
#pragma unroll
        for (int d = 0; d < DHD; d++) tt += sV[h * DHD + d] * gw1[d * HIDN + t];
        float contrib = siluf(tt) * gw2[t];
        float s = wave_sum(contrib);
        if ((t & 63) == 0) sRed[t >> 6] = s;
        __syncthreads();
        if (t == 0) gates[i * NHD + h] = 1.0f / (1.0f + __expf(-(sRed[0] + sRed[1] + gb2[0])));
        __syncthreads();
    }
}

// ---------------- K2: MFMA scores kernel (no x1 round-trip) ----------------
#define OFF_W1RT 0            // 128 n-rows x 72 bf16 (stride 144B) = 18432
#define OFF_QPB  18432        // 8x128 bf16 = 2048
#define OFF_W3T  20480        // 8x128 f32 = 4096
#define OFF_B1   24576        // 512
#define OFF_W1D  25088        // 512
#define OFF_B2   25600        // 512
#define OFF_AB3  26112        // 32
#define OFF_SDD  26144        // 16 f32 (dot) = 64 (pad to 128)
#define OFF_RBF  26272        // 16 rows x 72 bf16 (stride 144B) = 2304
#define OFF_R    28576        // 16 rows x 132 f32 (stride 528B) = 8448
#define SMEM_SZ  37024
#define OFF_STAGE 0           // W2T staging: 128 x 136 bf16 = 34816 (overlaid)

__global__ __launch_bounds__(256, 2) void k_scores_mfma(
    const float* __restrict__ coords, const float* __restrict__ mask,
    const float* __restrict__ centers, const float* __restrict__ widths,
    const float* __restrict__ aw1, const float* __restrict__ ab1,
    const float* __restrict__ aw2, const float* __restrict__ ab2,
    const float* __restrict__ aw3, const float* __restrict__ ab3,
    const unsigned short* __restrict__ Qpb, const unsigned short* __restrict__ Kpb,
    float* __restrict__ scores) {
    __shared__ __align__(16) char smem[SMEM_SZ];
    const int t = threadIdx.x;
    const int lane = t & 63;
    const int w = t >> 6;
    const int l15 = lane & 15;
    const int quad = lane >> 4;
    const int i = blockIdx.y;
    const int jb = blockIdx.x * 128;

    // phase0: stage W2T bf16 [n][k] stride 272B, pull B-frags into regs
    for (int idx = t; idx < HIDN * HIDN; idx += 256) {
        int k = idx >> 7, n = idx & 127;
        *(short*)(smem + OFF_STAGE + n * 272 + k * 2) = f2bf(aw2[idx]);
    }
    __syncthreads();
    bf16x8 BW2[8][4];
#pragma unroll
    for (int ct = 0; ct < 8; ct++)
#pragma unroll
        for (int ks = 0; ks < 4; ks++)
            BW2[ct][ks] = *(const bf16x8*)(smem + OFF_STAGE + (ct * 16 + l15) * 272 + ks * 64 + quad * 16);
    __syncthreads();
    // phase1: resident tables
    for (int idx = t; idx < NRB * HIDN; idx += 256) {
        int r = idx >> 7, n = idx & 127;
        *(short*)(smem + OFF_W1RT + n * 144 + r * 2) = f2bf(aw1[32 * HIDN + idx]);
    }
    {
        const unsigned int* qsrc = (const unsigned int*)(Qpb + (size_t)i * NHD * HIDN);
        for (int idx = t; idx < 512; idx += 256) *(unsigned int*)(smem + OFF_QPB + idx * 4) = qsrc[idx];
    }
    for (int idx = t; idx < HIDN * NHD; idx += 256) {
        int c = idx >> 3, h = idx & 7;
        *(float*)(smem + OFF_W3T + (h * 128 + c) * 4) = aw3[idx];
    }
    if (t < 128) {
        *(float*)(smem + OFF_B1 + t * 4) = ab1[t];
        *(float*)(smem + OFF_W1D + t * 4) = aw1[96 * HIDN + t];
        *(float*)(smem + OFF_B2 + t * 4) = ab2[t];
    }
    if (t < 8) *(float*)(smem + OFF_AB3 + t * 4) = ab3[t];
    const float cix = coords[i * 3], ciy = coords[i * 3 + 1], ciz = coords[i * 3 + 2];
    __syncthreads();

    for (int ch = 0; ch < 8; ch++) {
        const int j0 = jb + ch * 16;
        // (ab) rbf + dot
        {
            int r = t & 63, j4 = t >> 6;
            float cr = centers[r], rw = widths[r];
#pragma unroll
            for (int p = 0; p < 4; p++) {
                int j = j4 + p * 4;
                int jj = j0 + j;
                float jx = coords[jj * 3], jy = coords[jj * 3 + 1], jz = coords[jj * 3 + 2];
                float dx = cix - jx, dy = ciy - jy, dz = ciz - jz;
                float dist = sqrtf(dx * dx + dy * dy + dz * dz) + 1e-8f;
                dist = fminf(fmaxf(dist, 1e-8f), 1e8f);
                float dd = dist - cr;
                float val = (dist <= CUTF) ? __expf(-rw * dd * dd) : 0.0f;
                *(short*)(smem + OFF_RBF + j * 144 + r * 2) = f2bf(val);
            }
            if (t < 16) {
                int jj = j0 + t;
                float jx = coords[jj * 3], jy = coords[jj * 3 + 1], jz = coords[jj * 3 + 2];
                float dot = fminf(fmaxf(cix * jx + ciy * jy + ciz * jz, -1e8f), 1e8f);
                *(float*)(smem + OFF_SDD + t * 4) = dot;
            }
        }
        __syncthreads();
        // (c) R = b1 + rbf@W1r + dot*w1d via MFMA (K=64)
        {
            bf16x8 ra0 = *(const bf16x8*)(smem + OFF_RBF + l15 * 144 + quad * 16);
            bf16x8 ra1 = *(const bf16x8*)(smem + OFF_RBF + l15 * 144 + 64 + quad * 16);
#pragma unroll
            for (int cc = 0; cc < 2; cc++) {
                int ct = w + cc * 4;
                floatx4 acc = {0.f, 0.f, 0.f, 0.f};
                bf16x8 b0 = *(const bf16x8*)(smem + OFF_W1RT + (ct * 16 + l15) * 144 + quad * 16);
                bf16x8 b1f = *(const bf16x8*)(smem + OFF_W1RT + (ct * 16 + l15) * 144 + 64 + quad * 16);
                acc = MFMA16(ra0, b0, acc);
                acc = MFMA16(ra1, b1f, acc);
                int c = ct * 16 + l15;
                float b1v = *(const float*)(smem + OFF_B1 + c * 4);
                float w1dv = *(const float*)(smem + OFF_W1D + c * 4);
#pragma unroll
                for (int r = 0; r < 4; r++) {
                    int j = quad * 4 + r;
                    float dotv = *(const float*)(smem + OFF_SDD + j * 4);
                    *(float*)(smem + OFF_R + j * 528 + c * 4) = acc[r] + b1v + dotv * w1dv;
                }
            }
        }
        __syncthreads();
        // strips: wave w -> heads {w, w+4}; A-frags built in-register
#pragma unroll
        for (int hh = 0; hh < 2; hh++) {
            const int h = hh * 4 + w;
            const unsigned short* kpr = Kpb + ((size_t)(j0 + l15) * NHD + h) * HIDN;
            bf16x8 A[4];
#pragma unroll
            for (int f = 0; f < 4; f++) {
                int c8 = f * 32 + quad * 8;
                bf16x8 kp = *(const bf16x8*)(kpr + c8);
                bf16x8 qp = *(const bf16x8*)(smem + OFF_QPB + (h * 128 + c8) * 2);
                float4 r0 = *(const float4*)(smem + OFF_R + l15 * 528 + c8 * 4);
                float4 r1 = *(const float4*)(smem + OFF_R + l15 * 528 + c8 * 4 + 16);
                float rr[8] = {r0.x, r0.y, r0.z, r0.w, r1.x, r1.y, r1.z, r1.w};
                bf16x8 a;
#pragma unroll
                for (int e = 0; e < 8; e++) {
                    float x = silu_fast(bf2f(kp[e]) + bf2f(qp[e]) + rr[e]);
                    a[e] = f2bf(x);
                }
                A[f] = a;
            }
            float part[4] = {0.f, 0.f, 0.f, 0.f};
#pragma unroll
            for (int ct = 0; ct < 8; ct++) {
                floatx4 acc = {0.f, 0.f, 0.f, 0.f};
                acc = MFMA16(A[0], BW2[ct][0], acc);
                acc = MFMA16(A[1], BW2[ct][1], acc);
                acc = MFMA16(A[2], BW2[ct][2], acc);
                acc = MFMA16(A[3], BW2[ct][3], acc);
                int c = ct * 16 + l15;
                float b2v = *(const float*)(smem + OFF_B2 + c * 4);
                float w3v = *(const float*)(smem + OFF_W3T + (h * 128 + c) * 4);
#pragma unroll
                for (int r = 0; r < 4; r++)
                    part[r] += silu_fast(acc[r] + b2v) * w3v;
            }
#pragma unroll
            for (int off = 1; off < 16; off <<= 1) {
#pragma unroll
                for (int r = 0; r < 4; r++) part[r] += __shfl_xor(part[r], off, 64);
            }
            if (l15 == 0) {
                float ab3v = *(const float*)(smem + OFF_AB3 + h * 4);
#pragma unroll
                for (int r = 0; r < 4; r++) {
                    int j = quad * 4 + r;
                    float s = part[r] + ab3v + mask[(size_t)i * N + j0 + j];
                    s = fminf(fmaxf(s, -1e9f), 1e9f);
                    scores[((size_t)h * N + i) * N + j0 + j] = s;
                }
            }
        }
        __syncthreads();
    }
}

// K3: softmax + attn@V + coords out. 1 block per i, 4 waves, 2 heads/wave.
__global__ __launch_bounds__(256) void k_attn2(
    const float* __restrict__ scores, const float* __restrict__ v,
    const float* __restrict__ gates, const float* __restrict__ coords,
    float* __restrict__ upd, float* __restrict__ out) {
    __shared__ float sA[4][N];
    __shared__ float sCrd[N * 3];
    __shared__ float sC[NHD][3];
    int i = blockIdx.x, t = threadIdx.x, w = t >> 6, lane = t & 63;
    for (int idx = t; idx < N * 3; idx += 256) sCrd[idx] = coords[idx];
    float cix = coords[i * 3], ciy = coords[i * 3 + 1], ciz = coords[i * 3 + 2];
    __syncthreads();
    for (int hh = 0; hh < 2; hh++) {
        int h = hh * 4 + w;
        const float* srow = scores + ((size_t)h * N + i) * N;
        float s[6];
#pragma unroll
        for (int p = 0; p < 6; p++) s[p] = srow[lane + 64 * p];
        float m = s[0];
#pragma unroll
        for (int p = 1; p < 6; p++) m = fmaxf(m, s[p]);
        for (int off = 1; off < 64; off <<= 1) m = fmaxf(m, __shfl_xor(m, off, 64));
        float e[6], sum = 0.f;
#pragma unroll
        for (int p = 0; p < 6; p++) { e[p] = __expf(s[p] - m); sum += e[p]; }
        for (int off = 1; off < 64; off <<= 1) sum += __shfl_xor(sum, off, 64);
        float inv = 1.0f / sum;
#pragma unroll
        for (int p = 0; p < 6; p++) sA[w][lane + 64 * p] = e[p] * inv;
        __syncthreads();
        // feats: d4 = lane&3 (float4 of dims), grp = lane>>2
        int d4 = lane & 3, grp = lane >> 2;
        float4 f4 = {0.f, 0.f, 0.f, 0.f};
        for (int j = grp; j < N; j += 16) {
            float a = sA[w][j];
            float4 vv = *(const float4*)(v + j * HIDN + h * DHD + d4 * 4);
            f4.x += a * vv.x; f4.y += a * vv.y; f4.z += a * vv.z; f4.w += a * vv.w;
        }
#pragma unroll
        for (int off = 4; off < 64; off <<= 1) {
            f4.x += __shfl_xor(f4.x, off, 64);
            f4.y += __shfl_xor(f4.y, off, 64);
            f4.z += __shfl_xor(f4.z, off, 64);
            f4.w += __shfl_xor(f4.w, off, 64);
        }
        if (lane < 4) *(float4*)(upd + i * HIDN + h * DHD + lane * 4) = f4;
        // coords partial
        float cx = 0.f, cy = 0.f, cz = 0.f;
#pragma unroll
        for (int p = 0; p < 6; p++) {
            int j = lane + 64 * p;
            float a = sA[w][j];
            cx += a * (cix - sCrd[j * 3]);
            cy += a * (ciy - sCrd[j * 3 + 1]);
            cz += a * (ciz - sCrd[j * 3 + 2]);
        }
        for (int off = 1; off < 64; off <<= 1) {
            cx += __shfl_xor(cx, off, 64);
            cy += __shfl_xor(cy, off, 64);
            cz += __shfl_xor(cz, off, 64);
        }
        if (lane == 0) {
            float g = gates[i * NHD + h] * (1.0f / NHD);
            sC[h][0] = g * cx; sC[h][1] = g * cy; sC[h][2] = g * cz;
        }
        __syncthreads();
    }
    if (t < 3) {
        float acc = coords[i * 3 + t];
#pragma unroll
        for (int h = 0; h < NHD; h++) acc += sC[h][t];
        out[N * HIDN + i * 3 + t] = acc;
    }
}

// K4: y = ef + upd@wo + bo, LayerNorm
__global__ __launch_bounds__(128) void k_out(
    const float* __restrict__ ef, const float* __restrict__ upd,
    const float* __restrict__ wo, const float* __restrict__ bo,
    const float* __restrict__ lng, const float* __restrict__ lnb,
    float* __restrict__ out) {
    __shared__ float sU[HIDN];
    __shared__ float sR[2];
    int i = blockIdx.x, c = threadIdx.x;
    sU[c] = upd[i * HIDN + c];
    __syncthreads();
    float y = ef[i * HIDN + c] + bo[c];
#pragma unroll 8
    for (int cp = 0; cp < HIDN; cp++) y += sU[cp] * wo[cp * HIDN + c];
    float s = wave_sum(y);
    if ((c & 63) == 0) sR[c >> 6] = s;
    __syncthreads();
    float mu = (sR[0] + sR[1]) * (1.0f / HIDN);
    __syncthreads();
    float dv = y - mu;
    float s2 = wave_sum(dv * dv);
    if ((c & 63) == 0) sR[c >> 6] = s2;
    __syncthreads();
    float var = (sR[0] + sR[1]) * (1.0f / HIDN);
    out[i * HIDN + c] = dv * rsqrtf(var + 1e-5f) * lng[c] + lnb[c];
}

extern "C" void kernel_launch(void* const* d_in, const int* in_sizes, int n_in,
                              void* d_out, int out_size, void* d_ws, size_t ws_size,
                              hipStream_t stream) {
    const float* ef      = (const float*)d_in[0];
    const float* coords  = (const float*)d_in[1];
    const float* mask    = (const float*)d_in[2];
    const float* wq      = (const float*)d_in[3];
    const float* wk      = (const float*)d_in[4];
    const float* wv      = (const float*)d_in[5];
    const float* centers = (const float*)d_in[6];
    const float* widths  = (const float*)d_in[7];
    const float* aw1     = (const float*)d_in[8];
    const float* ab1     = (const float*)d_in[9];
    const float* aw2     = (const float*)d_in[10];
    const float* ab2     = (const float*)d_in[11];
    const float* aw3     = (const float*)d_in[12];
    const float* ab3     = (const float*)d_in[13];
    const float* gw1     = (const float*)d_in[14];
    const float* gb1     = (const float*)d_in[15];
    const float* gw2     = (const float*)d_in[16];
    const float* gb2     = (const float*)d_in[17];
    const float* wo      = (const float*)d_in[18];
    const float* bo      = (const float*)d_in[19];
    const float* lng     = (const float*)d_in[20];
    const float* lnb     = (const float*)d_in[21];
    float* ws = (float*)d_ws;
    float* v      = ws + WS_V;
    unsigned short* Qpb = (unsigned short*)(ws + WS_QPB);
    unsigned short* Kpb = (unsigned short*)(ws + WS_KPB);
    float* gates  = ws + WS_GATE;
    float* upd    = ws + WS_UPD;
    float* scores = ws + WS_SCORES;
    float* out = (float*)d_out;

    k_pre<<<N, 128, 0, stream>>>(ef, wq, wk, wv, aw1, gw1, gb1, gw2, gb2, v, Qpb, Kpb, gates);
    k_scores_mfma<<<dim3(3, N), 256, 0, stream>>>(
        coords, mask, centers, widths, aw1, ab1, aw2, ab2, aw3, ab3, Qpb, Kpb, scores);
    k_attn2<<<N, 256, 0, stream>>>(scores, v, gates, coords, upd, out);
    k_out<<<N, 128, 0, stream>>>(ef, upd, wo, bo, lng, lnb, out);
}